// Round 9
// baseline (1976.841 us; speedup 1.0000x reference)
//
#include <hip/hip_runtime.h>
#include <hip/hip_bf16.h>
#include <cmath>
#include <cstdint>
#include <cstddef>

#define NEG 0.2f

typedef __attribute__((ext_vector_type(8))) short bf16x8;
typedef __attribute__((ext_vector_type(4))) float f32x4;

// pack two f32 -> one dword of two bf16 (RNE); elem0 in low 16 bits
__device__ __forceinline__ unsigned pack2(float a, float b) {
  __hip_bfloat162 t = __float22bfloat162_rn(make_float2(a, b));
  return *reinterpret_cast<unsigned*>(&t);
}
__device__ __forceinline__ float2 unpack2(unsigned w) {
  __hip_bfloat162 t = *reinterpret_cast<__hip_bfloat162*>(&w);
  return __bfloat1622float2(t);
}

// ---------------------------------------------------------------------------
// Split-bf16 MFMA GEMM: C[m, ccol+c] = sum_k Arow(m)[k] * W[k, wcol+c] (+bias)
// A fp32 (split hi/lo on the fly in staging); W pre-split+transposed:
// Wh/Wl are bf16 [N][ldk] row-major (ldk = K padded to x32, zero-filled).
// Per element product: ah*bh + ah*bl + al*bh (al*bl dropped, ~2^-18 rel).
// Tile BM=BN=128, BK=32; 4 waves (2x2), per-wave 64x64 via 4x4 x 16x16x32.
// mode 0: Arow(m)=A+m*lda; mode 1: A+(ids[m]%mod)*lda; mode 2: [emb|att].
// flags bit0: += A[m, ccol+c] (residual; mode 0, lda==ldc).
// ---------------------------------------------------------------------------
__global__ __launch_bounds__(256) void gemm_k(
    const float* __restrict__ A, int lda,
    const int* __restrict__ ids, int mod,
    const unsigned short* __restrict__ Wh, const unsigned short* __restrict__ Wl,
    int ldk, int wcolBase, const float* __restrict__ bias,
    float* __restrict__ C, int ldc, int ccolBase,
    int K, int mode, int flags,
    const float* __restrict__ uemb, const float* __restrict__ iemb,
    const int* __restrict__ uids, const int* __restrict__ iids,
    const float* __restrict__ att, int Busers)
{
  // LDS: [128 rows][40 bf16] (pad 32->40 => 80B row stride, 16B-aligned blocks)
  __shared__ unsigned short Ah[128 * 40];
  __shared__ unsigned short Al[128 * 40];
  __shared__ unsigned short Bh[128 * 40];
  __shared__ unsigned short Bl[128 * 40];

  const int tid = threadIdx.x;
  const int m0 = blockIdx.x * 128;
  const int wcol = wcolBase + blockIdx.y * 128;
  const int ccol = ccolBase + blockIdx.y * 128;

  // staging binding: 2 threads per row, 16 elems (one 16-elem k-chunk) each
  const int rr = tid >> 1, q = tid & 1;

  // wave/frag binding
  const int wid = tid >> 6;
  const int l = tid & 63;
  const int wr = wid >> 1, wc = wid & 1;
  const int lr = l & 15;       // frag row(A)/col(B)
  const int kb = l >> 4;       // k-block 0..3 (8 elems each)

  int aoff[4], boff[4];
#pragma unroll
  for (int i = 0; i < 4; ++i) {
    aoff[i] = (wr * 64 + i * 16 + lr) * 40 + kb * 8;
    boff[i] = (wc * 64 + i * 16 + lr) * 40 + kb * 8;
  }

  f32x4 acc[4][4];
#pragma unroll
  for (int mi = 0; mi < 4; ++mi)
#pragma unroll
    for (int ni = 0; ni < 4; ++ni) acc[mi][ni] = (f32x4)0.f;

  // per-thread A row pointer(s)
  const float* arow = nullptr;
  const float* arow2 = nullptr;
  {
    const int row = m0 + rr;
    if (mode == 1) {
      const int gid = (int)(((unsigned)ids[row]) % (unsigned)mod);
      arow = A + (size_t)gid * lda;
    } else if (mode == 0) {
      arow = A + (size_t)row * lda;
    } else {
      if (row < Busers) arow = uemb + (size_t)uids[row] * 256;
      else              arow = iemb + (size_t)iids[row - Busers] * 256;
      arow2 = att + (size_t)row * 256;
    }
  }

  for (int k0 = 0; k0 < K; k0 += 32) {
    // ---- stage A (fp32 -> split bf16 hi/lo) ----
    {
      const float* sp; int kk;
      if (mode == 2) {
        if (k0 < 256) { sp = arow;  kk = k0; }
        else          { sp = arow2; kk = k0 - 256; }
      } else { sp = arow; kk = k0; }
      float f[16];
      if (k0 + 32 <= K) {
        const float4 x0 = *(const float4*)(sp + kk + q * 16);
        const float4 x1 = *(const float4*)(sp + kk + q * 16 + 4);
        const float4 x2 = *(const float4*)(sp + kk + q * 16 + 8);
        const float4 x3 = *(const float4*)(sp + kk + q * 16 + 12);
        f[0]=x0.x; f[1]=x0.y; f[2]=x0.z; f[3]=x0.w;
        f[4]=x1.x; f[5]=x1.y; f[6]=x1.z; f[7]=x1.w;
        f[8]=x2.x; f[9]=x2.y; f[10]=x2.z; f[11]=x2.w;
        f[12]=x3.x; f[13]=x3.y; f[14]=x3.z; f[15]=x3.w;
      } else {                      // K tail (text K=1000): zero-pad
#pragma unroll
        for (int j = 0; j < 16; ++j) {
          const int kg = k0 + q * 16 + j;
          f[j] = (kg < K) ? sp[kk + q * 16 + j] : 0.f;
        }
      }
      unsigned hw[8], lw[8];
#pragma unroll
      for (int p = 0; p < 8; ++p) {
        const unsigned h = pack2(f[2*p], f[2*p+1]);
        const float2 hf = unpack2(h);
        lw[p] = pack2(f[2*p] - hf.x, f[2*p+1] - hf.y);
        hw[p] = h;
      }
      uint4 v;
      const int sb = rr * 40 + q * 16;
      v.x=hw[0]; v.y=hw[1]; v.z=hw[2]; v.w=hw[3]; *(uint4*)&Ah[sb] = v;
      v.x=hw[4]; v.y=hw[5]; v.z=hw[6]; v.w=hw[7]; *(uint4*)&Ah[sb + 8] = v;
      v.x=lw[0]; v.y=lw[1]; v.z=lw[2]; v.w=lw[3]; *(uint4*)&Al[sb] = v;
      v.x=lw[4]; v.y=lw[5]; v.z=lw[6]; v.w=lw[7]; *(uint4*)&Al[sb + 8] = v;
    }
    // ---- stage B (pre-split bf16, transposed [n][k]: straight copy) ----
    {
      const size_t wb = (size_t)(wcol + rr) * ldk + k0 + q * 16;
      const int sb = rr * 40 + q * 16;
      *(uint4*)&Bh[sb]     = *(const uint4*)(Wh + wb);
      *(uint4*)&Bh[sb + 8] = *(const uint4*)(Wh + wb + 8);
      *(uint4*)&Bl[sb]     = *(const uint4*)(Wl + wb);
      *(uint4*)&Bl[sb + 8] = *(const uint4*)(Wl + wb + 8);
    }
    __syncthreads();
    // ---- fragments + MFMA ----
    bf16x8 fah[4], fal[4], fbh[4], fbl[4];
#pragma unroll
    for (int i = 0; i < 4; ++i) {
      fah[i] = *(const bf16x8*)&Ah[aoff[i]];
      fal[i] = *(const bf16x8*)&Al[aoff[i]];
      fbh[i] = *(const bf16x8*)&Bh[boff[i]];
      fbl[i] = *(const bf16x8*)&Bl[boff[i]];
    }
#pragma unroll
    for (int mi = 0; mi < 4; ++mi)
#pragma unroll
      for (int ni = 0; ni < 4; ++ni) {
        acc[mi][ni] = __builtin_amdgcn_mfma_f32_16x16x32_bf16(fah[mi], fbh[ni], acc[mi][ni], 0, 0, 0);
        acc[mi][ni] = __builtin_amdgcn_mfma_f32_16x16x32_bf16(fah[mi], fbl[ni], acc[mi][ni], 0, 0, 0);
        acc[mi][ni] = __builtin_amdgcn_mfma_f32_16x16x32_bf16(fal[mi], fbh[ni], acc[mi][ni], 0, 0, 0);
      }
    __syncthreads();
  }

  // ---- epilogue: C/D layout col=lane&15, row=(lane>>4)*4+j (m91-verified) ----
#pragma unroll
  for (int ni = 0; ni < 4; ++ni) {
    const int col = ccol + wc * 64 + ni * 16 + lr;
    const float bv = bias ? bias[wcol + wc * 64 + ni * 16 + lr] : 0.f;
#pragma unroll
    for (int mi = 0; mi < 4; ++mi) {
#pragma unroll
      for (int j = 0; j < 4; ++j) {
        const int row = m0 + wr * 64 + mi * 16 + kb * 4 + j;
        float o = acc[mi][ni][j] + bv;
        if (flags & 1) o += A[(size_t)row * lda + col];
        C[(size_t)row * ldc + col] = o;
      }
    }
  }
}

// ---------------------------------------------------------------------------
// Weight prep: W[K][N] fp32 -> Wh/Wl bf16 [N][ldk] (transposed, zero-padded)
// ---------------------------------------------------------------------------
__global__ void wsplit_k(const float* __restrict__ W, int Ncols, int K,
                         int ldkShift, unsigned short* __restrict__ Wh,
                         unsigned short* __restrict__ Wl)
{
  const int i = blockIdx.x * 256 + threadIdx.x;
  const int ldk = 1 << ldkShift;
  const int n = i >> ldkShift;
  const int k = i & (ldk - 1);
  if (n >= Ncols) return;
  const float v = (k < K) ? W[(size_t)k * Ncols + n] : 0.f;
  const unsigned u = __float_as_uint(v);
  const unsigned r = u + 0x7fffu + ((u >> 16) & 1);   // RNE to bf16
  const unsigned short h = (unsigned short)(r >> 16);
  const float hf = __uint_as_float(((unsigned)h) << 16);
  const float res = v - hf;                            // exact (Sterbenz)
  const unsigned u2 = __float_as_uint(res);
  const unsigned r2 = u2 + 0x7fffu + ((u2 >> 16) & 1);
  Wh[i] = h;
  Wl[i] = (unsigned short)(r2 >> 16);
}

// ---------------------------------------------------------------------------
// es/ed: per node, per head, dot(h[node,head,:], a_{s,d}[head,:])
// ---------------------------------------------------------------------------
__global__ __launch_bounds__(256) void esed_k(const float* __restrict__ h,
    const float* __restrict__ as, const float* __restrict__ ad,
    float* __restrict__ es, float* __restrict__ ed, int n)
{
  const int wv = blockIdx.x * 4 + (threadIdx.x >> 6);
  const int lane = threadIdx.x & 63;
  if (wv >= n) return;
  const float4 hv = *(const float4*)(h + (size_t)wv * 256 + lane * 4);
  const int head = lane >> 4;
  const int doff = (lane & 15) * 4;
  const float* asp = as + head * 64 + doff;
  const float* adp = ad + head * 64 + doff;
  float ps = hv.x*asp[0] + hv.y*asp[1] + hv.z*asp[2] + hv.w*asp[3];
  float pd = hv.x*adp[0] + hv.y*adp[1] + hv.z*adp[2] + hv.w*adp[3];
#pragma unroll
  for (int mask = 1; mask < 16; mask <<= 1) {
    ps += __shfl_xor(ps, mask);
    pd += __shfl_xor(pd, mask);
  }
  if ((lane & 15) == 0) {
    es[(size_t)wv * 4 + head] = ps;
    ed[(size_t)wv * 4 + head] = pd;
  }
}

// ---------------------------------------------------------------------------
// Per-dst online-softmax aggregation + gat bias + LayerNorm + ReLU, fused.
// ---------------------------------------------------------------------------
__global__ __launch_bounds__(256) void agg_k(const float* __restrict__ h,
    const float* __restrict__ es, const float* __restrict__ ed,
    const int* __restrict__ rowptr, const int* __restrict__ srclist,
    const float* __restrict__ gb, const float* __restrict__ gamma,
    const float* __restrict__ beta, float* __restrict__ xout, int n)
{
  const int wv = blockIdx.x * 4 + (threadIdx.x >> 6);
  const int lane = threadIdx.x & 63;
  if (wv >= n) return;
  const int head = lane >> 4;
  const int start = rowptr[wv], end = rowptr[wv + 1];
  const float edv = ed[(size_t)wv * 4 + head];
  float m = -INFINITY, den = 0.f;
  float ax = 0.f, ay = 0.f, az = 0.f, aw = 0.f;
  for (int p = start; p < end; ++p) {
    const int s = srclist[p];
    float ev = es[(size_t)s * 4 + head] + edv;
    ev = ev > 0.f ? ev : NEG * ev;
    const float nm = fmaxf(m, ev);
    const float sc = expf(m - nm);
    const float w = expf(ev - nm);
    den = den * sc + w;
    const float4 hv = *(const float4*)(h + (size_t)s * 256 + lane * 4);
    ax = ax * sc + w * hv.x;
    ay = ay * sc + w * hv.y;
    az = az * sc + w * hv.z;
    aw = aw * sc + w * hv.w;
    m = nm;
  }
  const float inv = 1.f / (den + 1e-16f);
  const int c = lane * 4;
  const float o0 = ax * inv + gb[c + 0];
  const float o1 = ay * inv + gb[c + 1];
  const float o2 = az * inv + gb[c + 2];
  const float o3 = aw * inv + gb[c + 3];
  float s1 = o0 + o1 + o2 + o3;
  float s2 = o0*o0 + o1*o1 + o2*o2 + o3*o3;
#pragma unroll
  for (int mask = 1; mask < 64; mask <<= 1) {
    s1 += __shfl_xor(s1, mask);
    s2 += __shfl_xor(s2, mask);
  }
  const float mu = s1 * (1.f / 256.f);
  const float var = s2 * (1.f / 256.f) - mu * mu;
  const float rs = rsqrtf(var + 1e-5f);
  float4 o;
  o.x = fmaxf(0.f, (o0 - mu) * rs * gamma[c + 0] + beta[c + 0]);
  o.y = fmaxf(0.f, (o1 - mu) * rs * gamma[c + 1] + beta[c + 1]);
  o.z = fmaxf(0.f, (o2 - mu) * rs * gamma[c + 2] + beta[c + 2]);
  o.w = fmaxf(0.f, (o3 - mu) * rs * gamma[c + 3] + beta[c + 3]);
  *(float4*)(xout + (size_t)wv * 256 + c) = o;
}

// ---------------------------------------------------------------------------
// CSR build helpers
// ---------------------------------------------------------------------------
__global__ void zero_k(int* __restrict__ p, int n) {
  const int i = blockIdx.x * 256 + threadIdx.x;
  if (i < n) p[i] = 0;
}
__global__ void count_k(const int* __restrict__ dst, int* __restrict__ counts, int E) {
  const int e = blockIdx.x * 256 + threadIdx.x;
  if (e < E) atomicAdd(&counts[dst[e]], 1);
}
__global__ __launch_bounds__(256) void scan1_k(const int* __restrict__ counts,
    int* __restrict__ rowptr, int* __restrict__ bsums, int n)
{
  __shared__ int sd[256];
  const int tid = threadIdx.x;
  const int base = blockIdx.x * 1024 + tid * 4;
  int a0 = base + 0 < n ? counts[base + 0] : 0;
  int a1 = base + 1 < n ? counts[base + 1] : 0;
  int a2 = base + 2 < n ? counts[base + 2] : 0;
  int a3 = base + 3 < n ? counts[base + 3] : 0;
  const int t = a0 + a1 + a2 + a3;
  sd[tid] = t;
  __syncthreads();
  for (int off = 1; off < 256; off <<= 1) {
    int v = 0;
    if (tid >= off) v = sd[tid - off];
    __syncthreads();
    sd[tid] += v;
    __syncthreads();
  }
  const int excl = sd[tid] - t;
  if (base + 0 < n) rowptr[base + 0] = excl;
  if (base + 1 < n) rowptr[base + 1] = excl + a0;
  if (base + 2 < n) rowptr[base + 2] = excl + a0 + a1;
  if (base + 3 < n) rowptr[base + 3] = excl + a0 + a1 + a2;
  if (tid == 255) bsums[blockIdx.x] = sd[255];
}
__global__ __launch_bounds__(256) void scan2_k(int* __restrict__ bsums, int nb) {
  __shared__ int sd[256];
  const int tid = threadIdx.x;
  const int v = tid < nb ? bsums[tid] : 0;
  sd[tid] = v;
  __syncthreads();
  for (int off = 1; off < 256; off <<= 1) {
    int u = 0;
    if (tid >= off) u = sd[tid - off];
    __syncthreads();
    sd[tid] += u;
    __syncthreads();
  }
  if (tid < nb) bsums[tid] = sd[tid] - v;
}
__global__ void scan3_k(int* __restrict__ rowptr, const int* __restrict__ bsums,
                        int n, int E) {
  const int i = blockIdx.x * 256 + threadIdx.x;
  if (i < n) rowptr[i] += bsums[i >> 10];
  if (i == 0) rowptr[n] = E;
}
__global__ void copy_k(const int* __restrict__ a, int* __restrict__ b, int n) {
  const int i = blockIdx.x * 256 + threadIdx.x;
  if (i < n) b[i] = a[i];
}
__global__ void scatter_k(const int* __restrict__ srcA, const int* __restrict__ dstA,
                          int* __restrict__ cursor, int* __restrict__ srclist, int E) {
  const int e = blockIdx.x * 256 + threadIdx.x;
  if (e < E) {
    const int d = dstA[e];
    const int p = atomicAdd(&cursor[d], 1);
    srclist[p] = srcA[e];
  }
}

// ---------------------------------------------------------------------------
// Final: scores = dot(u, v), plus copy u, v into d_out
// ---------------------------------------------------------------------------
__global__ __launch_bounds__(256) void out_k(const float* __restrict__ x,
                                             float* __restrict__ out, int B)
{
  const int wv = blockIdx.x * 4 + (threadIdx.x >> 6);
  const int lane = threadIdx.x & 63;
  if (wv >= B) return;
  const float4 u = *(const float4*)(x + (size_t)wv * 256 + lane * 4);
  const float4 v = *(const float4*)(x + (size_t)(B + wv) * 256 + lane * 4);
  *(float4*)(out + (size_t)B + (size_t)wv * 256 + lane * 4) = u;
  *(float4*)(out + (size_t)B + (size_t)B * 256 + (size_t)wv * 256 + lane * 4) = v;
  float d = u.x*v.x + u.y*v.y + u.z*v.z + u.w*v.w;
#pragma unroll
  for (int mask = 1; mask < 64; mask <<= 1) d += __shfl_xor(d, mask);
  if (lane == 0) out[wv] = d;
}

// ---------------------------------------------------------------------------
extern "C" void kernel_launch(void* const* d_in, const int* in_sizes, int n_in,
                              void* d_out, int out_size, void* d_ws, size_t ws_size,
                              hipStream_t stream) {
  const float* text  = (const float*)d_in[0];
  const float* image = (const float*)d_in[1];
  const float* uemb  = (const float*)d_in[2];
  const float* iemb  = (const float*)d_in[3];
  const float* ut_W = (const float*)d_in[4];  const float* ut_b = (const float*)d_in[5];
  const float* ui_W = (const float*)d_in[6];  const float* ui_b = (const float*)d_in[7];
  const float* it_W = (const float*)d_in[8];  const float* it_b = (const float*)d_in[9];
  const float* ii_W = (const float*)d_in[10]; const float* ii_b = (const float*)d_in[11];
  const float* ua_Wv = (const float*)d_in[12]; const float* ua_bv = (const float*)d_in[13];
  const float* ua_Wo = (const float*)d_in[14]; const float* ua_bo = (const float*)d_in[15];
  const float* ia_Wv = (const float*)d_in[16]; const float* ia_bv = (const float*)d_in[17];
  const float* ia_Wo = (const float*)d_in[18]; const float* ia_bo = (const float*)d_in[19];
  const float* gat_W[3] = {(const float*)d_in[20], (const float*)d_in[21], (const float*)d_in[22]};
  const float* att_src = (const float*)d_in[23];
  const float* att_dst = (const float*)d_in[24];
  const float* gat_b   = (const float*)d_in[25];
  const float* res_W   = (const float*)d_in[26];
  const float* res_b   = (const float*)d_in[27];
  const float* ln_g    = (const float*)d_in[28];
  const float* ln_b    = (const float*)d_in[29];
  const int* user_ids = (const int*)d_in[30];
  const int* item_ids = (const int*)d_in[31];
  const int* edge     = (const int*)d_in[32];

  const int Tn = in_sizes[0] / 1000;
  const int In = in_sizes[1] / 512;
  const int B  = in_sizes[30];
  const int E  = in_sizes[32] / 2;
  const int n  = 2 * B;
  const int* esrc = edge;
  const int* edst = edge + E;

  const size_t F = (size_t)n * 256;
  float* tbuf = (float*)d_ws;       // mm -> att -> res output
  float* hbuf = tbuf + F;           // t2 -> h per layer
  float* xbuf = hbuf + F;           // x after each GAT layer
  float* es   = xbuf + F;
  float* ed   = es + (size_t)n * 4;
  int* counts  = (int*)(ed + (size_t)n * 4);
  int* rowptr  = counts + n;
  int* cursor  = rowptr + (n + 4);  // +4 keeps the ushort region 16B-aligned
  int* srclist = cursor + n;
  int* bsums   = srclist + E;
  unsigned short* WH = (unsigned short*)(bsums + 256);
  unsigned short* WL = WH + 1048576;
  const int nb = (n + 1023) / 1024;

  const dim3 blk(256);
  const float* NF = nullptr;
  const int* NI = nullptr;

  // ---- weight prep: transpose + split to bf16 hi/lo (13 small kernels) ----
  // offsets (ushorts): see per-call comments; ldk padded to pow2 >= K
  wsplit_k<<<dim3(512), blk, 0, stream>>>(ut_W, 128, 1000, 10, WH + 0,      WL + 0);
  wsplit_k<<<dim3(256), blk, 0, stream>>>(ui_W, 128, 512,  9,  WH + 131072, WL + 131072);
  wsplit_k<<<dim3(512), blk, 0, stream>>>(it_W, 128, 1000, 10, WH + 196608, WL + 196608);
  wsplit_k<<<dim3(256), blk, 0, stream>>>(ii_W, 128, 512,  9,  WH + 327680, WL + 327680);
  wsplit_k<<<dim3(256), blk, 0, stream>>>(ua_Wv, 256, 256, 8,  WH + 393216, WL + 393216);
  wsplit_k<<<dim3(256), blk, 0, stream>>>(ua_Wo, 256, 256, 8,  WH + 458752, WL + 458752);
  wsplit_k<<<dim3(256), blk, 0, stream>>>(ia_Wv, 256, 256, 8,  WH + 524288, WL + 524288);
  wsplit_k<<<dim3(256), blk, 0, stream>>>(ia_Wo, 256, 256, 8,  WH + 589824, WL + 589824);
  wsplit_k<<<dim3(512), blk, 0, stream>>>(gat_W[0], 256, 512, 9, WH + 655360, WL + 655360);
  wsplit_k<<<dim3(256), blk, 0, stream>>>(gat_W[1], 256, 256, 8, WH + 786432, WL + 786432);
  wsplit_k<<<dim3(256), blk, 0, stream>>>(gat_W[2], 256, 256, 8, WH + 851968, WL + 851968);
  wsplit_k<<<dim3(256), blk, 0, stream>>>(res_W,          256, 256, 8, WH + 917504, WL + 917504);
  wsplit_k<<<dim3(256), blk, 0, stream>>>(res_W + 65536,  256, 256, 8, WH + 983040, WL + 983040);

  // ---- Phase A: modality projections -> mm (in tbuf) ----
  gemm_k<<<dim3(B/128, 1), blk, 0, stream>>>(text, 1000, user_ids, Tn,
      WH + 0, WL + 0, 1024, 0, ut_b, tbuf, 256, 0, 1000, 1, 0, NF, NF, NI, NI, NF, 0);
  gemm_k<<<dim3(B/128, 1), blk, 0, stream>>>(image, 512, user_ids, In,
      WH + 131072, WL + 131072, 512, 0, ui_b, tbuf, 256, 128, 512, 1, 0, NF, NF, NI, NI, NF, 0);
  gemm_k<<<dim3(B/128, 1), blk, 0, stream>>>(text, 1000, item_ids, Tn,
      WH + 196608, WL + 196608, 1024, 0, it_b, tbuf + (size_t)B*256, 256, 0, 1000, 1, 0, NF, NF, NI, NI, NF, 0);
  gemm_k<<<dim3(B/128, 1), blk, 0, stream>>>(image, 512, item_ids, In,
      WH + 327680, WL + 327680, 512, 0, ii_b, tbuf + (size_t)B*256, 256, 128, 512, 1, 0, NF, NF, NI, NI, NF, 0);

  // ---- attention MLP: t2 = mm@Wv+bv (hbuf), att = t2@Wo+bo (tbuf) ----
  gemm_k<<<dim3(B/128, 2), blk, 0, stream>>>(tbuf, 256, NI, 0,
      WH + 393216, WL + 393216, 256, 0, ua_bv, hbuf, 256, 0, 256, 0, 0, NF, NF, NI, NI, NF, 0);
  gemm_k<<<dim3(B/128, 2), blk, 0, stream>>>(tbuf + (size_t)B*256, 256, NI, 0,
      WH + 524288, WL + 524288, 256, 0, ia_bv, hbuf + (size_t)B*256, 256, 0, 256, 0, 0, NF, NF, NI, NI, NF, 0);
  gemm_k<<<dim3(B/128, 2), blk, 0, stream>>>(hbuf, 256, NI, 0,
      WH + 458752, WL + 458752, 256, 0, ua_bo, tbuf, 256, 0, 256, 0, 0, NF, NF, NI, NI, NF, 0);
  gemm_k<<<dim3(B/128, 2), blk, 0, stream>>>(hbuf + (size_t)B*256, 256, NI, 0,
      WH + 589824, WL + 589824, 256, 0, ia_bo, tbuf + (size_t)B*256, 256, 0, 256, 0, 0, NF, NF, NI, NI, NF, 0);

  // ---- CSR build (by dst) ----
  zero_k<<<dim3((n+255)/256), blk, 0, stream>>>(counts, n);
  count_k<<<dim3((E+255)/256), blk, 0, stream>>>(edst, counts, E);
  scan1_k<<<dim3(nb), blk, 0, stream>>>(counts, rowptr, bsums, n);
  scan2_k<<<dim3(1), blk, 0, stream>>>(bsums, nb);
  scan3_k<<<dim3((n+255)/256), blk, 0, stream>>>(rowptr, bsums, n, E);
  copy_k<<<dim3((n+255)/256), blk, 0, stream>>>(rowptr, cursor, n);
  scatter_k<<<dim3((E+255)/256), blk, 0, stream>>>(esrc, edst, cursor, srclist, E);

  // ---- 3 GAT layers ----
  for (int l = 0; l < 3; ++l) {
    if (l == 0) {
      // h = [emb | att] @ W0   (K=512, A assembled in the loader)
      gemm_k<<<dim3(n/128, 2), blk, 0, stream>>>(NF, 0, NI, 0,
          WH + 655360, WL + 655360, 512, 0, NF, hbuf, 256, 0, 512, 2, 0,
          uemb, iemb, user_ids, item_ids, tbuf, B);
    } else {
      // res: tbuf = xbuf + xbuf@res_W + res_b
      const int roff = (l == 1) ? 917504 : 983040;
      gemm_k<<<dim3(n/128, 2), blk, 0, stream>>>(xbuf, 256, NI, 0,
          WH + roff, WL + roff, 256, 0, res_b + (size_t)(l-1)*256,
          tbuf, 256, 0, 256, 0, 1, NF, NF, NI, NI, NF, 0);
      // h = tbuf @ Wl
      const int goff = (l == 1) ? 786432 : 851968;
      gemm_k<<<dim3(n/128, 2), blk, 0, stream>>>(tbuf, 256, NI, 0,
          WH + goff, WL + goff, 256, 0, NF, hbuf, 256, 0, 256, 0, 0, NF, NF, NI, NI, NF, 0);
    }
    esed_k<<<dim3((n+3)/4), blk, 0, stream>>>(hbuf, att_src + (size_t)l*256,
        att_dst + (size_t)l*256, es, ed, n);
    agg_k<<<dim3((n+3)/4), blk, 0, stream>>>(hbuf, es, ed, rowptr, srclist,
        gat_b + (size_t)l*256, ln_g + (size_t)l*256, ln_b + (size_t)l*256, xbuf, n);
  }

  // ---- output: scores + u + v ----
  out_k<<<dim3((B+3)/4), blk, 0, stream>>>(xbuf, (float*)d_out, B);
}